// Round 19
// baseline (674.917 us; speedup 1.0000x reference)
//
#include <hip/hip_runtime.h>
#include <hip/hip_bf16.h>
#include <math.h>

// Problem constants
#define BB 4
#define LL 2048
#define DD 512
#define HH 8
#define NLAYER 4
#define VV 258
#define WW 8
#define HDIM 64
#define MM (BB * LL)   // 8192 rows
#define VPAD 384       // logits weight rows padded to tile multiple

// 0.125 * log2(e): QK^T scale, folded into Q at the qkv-GEMM epilogue
#define C8 0.18033688f

typedef __attribute__((ext_vector_type(8))) short short8v;
typedef __attribute__((ext_vector_type(4))) float float4v;

typedef __attribute__((address_space(3))) unsigned int lds_u32;
typedef const __attribute__((address_space(1))) unsigned int glb_u32;

__device__ __forceinline__ unsigned short f2bf(float x) {
    unsigned int u = __float_as_uint(x);
    unsigned int r = (u + 0x7fffu + ((u >> 16) & 1u)) >> 16;
    return (unsigned short)r;
}
__device__ __forceinline__ float bf2f(unsigned short u) {
    return __uint_as_float((unsigned)u << 16);
}

__device__ __forceinline__ unsigned lds_addr(const void* p) {
    return (unsigned)(size_t)(__attribute__((address_space(3))) const void*)p;
}

__device__ __forceinline__ float gelu_tanh(float v) {
    float a = 0.044715f * v * v;
    float u = fminf(fmaf(a, v, v) * 2.3022077f, 80.f);
    float e = __builtin_amdgcn_exp2f(u);
    return v * e * __builtin_amdgcn_rcpf(e + 1.f);
}

// ---------------------------------------------------------------------------
// Fused weight conversion: all four layer-weight arrays + padded out_w.
// ---------------------------------------------------------------------------
#define E0 (NLAYER * 3 * DD * DD)          // 3,145,728
#define E1 (E0 + NLAYER * DD * DD)         // 4,194,304
#define E2 (E1 + NLAYER * 4 * DD * DD)     // 8,388,608
#define E3 (E2 + NLAYER * 4 * DD * DD)     // 12,582,912
#define E4 (E3 + VPAD * DD)                // 12,779,520

__global__ __launch_bounds__(256)
void cvt_all_kernel(const float* __restrict__ qkv_w, const float* __restrict__ ao_w,
                    const float* __restrict__ ff1_w, const float* __restrict__ ff2_w,
                    const float* __restrict__ out_w, unsigned short* __restrict__ dst)
{
    int i = (blockIdx.x * 256 + threadIdx.x) * 4;
    float4 v;
    if (i < E0)      v = *reinterpret_cast<const float4*>(qkv_w + i);
    else if (i < E1) v = *reinterpret_cast<const float4*>(ao_w + (i - E0));
    else if (i < E2) v = *reinterpret_cast<const float4*>(ff1_w + (i - E1));
    else if (i < E3) v = *reinterpret_cast<const float4*>(ff2_w + (i - E2));
    else {
        int idx = i - E3;
        if ((idx >> 9) < VV) v = *reinterpret_cast<const float4*>(out_w + idx);
        else                 v = (float4){0.f, 0.f, 0.f, 0.f};
    }
    uint2 pk;
    pk.x = (unsigned)f2bf(v.x) | ((unsigned)f2bf(v.y) << 16);
    pk.y = (unsigned)f2bf(v.z) | ((unsigned)f2bf(v.w) << 16);
    *reinterpret_cast<uint2*>(dst + i) = pk;
}

// ---------------------------------------------------------------------------
// Kernel 1: fused token embedding + entropy feature + LN1(layer 0)
// ---------------------------------------------------------------------------
__global__ __launch_bounds__(256)
void embed_ln_kernel(const int* __restrict__ x,
                     const float* __restrict__ emb,
                     const float* __restrict__ ent_w,
                     const float* __restrict__ ent_b,
                     const float* __restrict__ ln_s,
                     const float* __restrict__ ln_b,
                     unsigned short* __restrict__ h,
                     unsigned short* __restrict__ g)
{
    int w = threadIdx.x >> 6, lane = threadIdx.x & 63;
    int row = blockIdx.x * 4 + w;
    int b = row / LL, l = row % LL;

    float ent = 0.f;
    if (l <= LL - WW) {
        int win[WW];
        #pragma unroll
        for (int i = 0; i < WW; i++) win[i] = x[b * LL + l + i];
        float s = 0.f;
        #pragma unroll
        for (int i = 0; i < WW; i++) {
            if (win[i] < 256) {
                int c = 0;
                #pragma unroll
                for (int j = 0; j < WW; j++) c += (win[j] == win[i]) ? 1 : 0;
                s += log2f((float)c * 0.125f + 1e-10f);
            }
        }
        ent = -s * 0.125f;
    }

    int tok = x[row];
    const float* erow = emb + (size_t)tok * DD + lane * 8;
    float v[8], ew[8], eb[8];
    *reinterpret_cast<float4*>(v)      = *reinterpret_cast<const float4*>(erow);
    *reinterpret_cast<float4*>(v + 4)  = *reinterpret_cast<const float4*>(erow + 4);
    *reinterpret_cast<float4*>(ew)     = *reinterpret_cast<const float4*>(ent_w + lane * 8);
    *reinterpret_cast<float4*>(ew + 4) = *reinterpret_cast<const float4*>(ent_w + lane * 8 + 4);
    *reinterpret_cast<float4*>(eb)     = *reinterpret_cast<const float4*>(ent_b + lane * 8);
    *reinterpret_cast<float4*>(eb + 4) = *reinterpret_cast<const float4*>(ent_b + lane * 8 + 4);

    float sum = 0.f, sq = 0.f;
    #pragma unroll
    for (int i = 0; i < 8; i++) {
        v[i] = v[i] + ent * ew[i] + eb[i];
        sum += v[i]; sq += v[i] * v[i];
    }
    unsigned int hpk[4];
    #pragma unroll
    for (int i = 0; i < 4; i++)
        hpk[i] = (unsigned)f2bf(v[2*i]) | ((unsigned)f2bf(v[2*i+1]) << 16);
    *reinterpret_cast<uint4*>(h + (size_t)row * DD + lane * 8) =
        *reinterpret_cast<const uint4*>(hpk);

    #pragma unroll
    for (int off = 32; off > 0; off >>= 1) {
        sum += __shfl_xor(sum, off);
        sq  += __shfl_xor(sq, off);
    }
    float mu = sum * (1.f / DD);
    float var = sq * (1.f / DD) - mu * mu;
    float rstd = rsqrtf(var + 1e-5f);

    float s8[8], bi[8];
    *reinterpret_cast<float4*>(s8)     = *reinterpret_cast<const float4*>(ln_s + lane * 8);
    *reinterpret_cast<float4*>(s8 + 4) = *reinterpret_cast<const float4*>(ln_s + lane * 8 + 4);
    *reinterpret_cast<float4*>(bi)     = *reinterpret_cast<const float4*>(ln_b + lane * 8);
    *reinterpret_cast<float4*>(bi + 4) = *reinterpret_cast<const float4*>(ln_b + lane * 8 + 4);

    unsigned int pk[4];
    #pragma unroll
    for (int i = 0; i < 4; i++) {
        unsigned short lo = f2bf((v[2*i]   - mu) * rstd * s8[2*i]   + bi[2*i]);
        unsigned short hi = f2bf((v[2*i+1] - mu) * rstd * s8[2*i+1] + bi[2*i+1]);
        pk[i] = (unsigned)lo | ((unsigned)hi << 16);
    }
    *reinterpret_cast<uint4*>(g + (size_t)row * DD + lane * 8) =
        *reinterpret_cast<const uint4*>(pk);
}

// ---------------------------------------------------------------------------
// Kernel 2: LayerNorm (bf16 in, bf16 out). One wave per row, 4 rows/block.
// ---------------------------------------------------------------------------
__global__ __launch_bounds__(256)
void ln_kernel(const unsigned short* __restrict__ h,
               const float* __restrict__ scale,
               const float* __restrict__ bias,
               unsigned short* __restrict__ g)
{
    int w = threadIdx.x >> 6, lane = threadIdx.x & 63;
    int row = blockIdx.x * 4 + w;

    uint4 raw = *reinterpret_cast<const uint4*>(h + (size_t)row * DD + lane * 8);
    const unsigned* rw = reinterpret_cast<const unsigned*>(&raw);
    float v[8];
    #pragma unroll
    for (int i = 0; i < 4; i++) {
        v[2*i]   = __uint_as_float(rw[i] << 16);
        v[2*i+1] = __uint_as_float(rw[i] & 0xffff0000u);
    }

    float sum = 0.f, sq = 0.f;
    #pragma unroll
    for (int i = 0; i < 8; i++) { sum += v[i]; sq += v[i] * v[i]; }
    #pragma unroll
    for (int off = 32; off > 0; off >>= 1) {
        sum += __shfl_xor(sum, off);
        sq  += __shfl_xor(sq, off);
    }
    float mu = sum * (1.f / DD);
    float var = sq * (1.f / DD) - mu * mu;
    float rstd = rsqrtf(var + 1e-5f);

    float s[8], bi[8];
    *reinterpret_cast<float4*>(s)      = *reinterpret_cast<const float4*>(scale + lane * 8);
    *reinterpret_cast<float4*>(s + 4)  = *reinterpret_cast<const float4*>(scale + lane * 8 + 4);
    *reinterpret_cast<float4*>(bi)     = *reinterpret_cast<const float4*>(bias + lane * 8);
    *reinterpret_cast<float4*>(bi + 4) = *reinterpret_cast<const float4*>(bias + lane * 8 + 4);

    unsigned int pk[4];
    #pragma unroll
    for (int i = 0; i < 4; i++) {
        unsigned short lo = f2bf((v[2*i]   - mu) * rstd * s[2*i]   + bi[2*i]);
        unsigned short hi = f2bf((v[2*i+1] - mu) * rstd * s[2*i+1] + bi[2*i+1]);
        pk[i] = (unsigned)lo | ((unsigned)hi << 16);
    }
    *reinterpret_cast<uint4*>(g + (size_t)row * DD + lane * 8) =
        *reinterpret_cast<const uint4*>(pk);
}

// ---------------------------------------------------------------------------
// Kernel 3: MFMA GEMM (2-phase, MT=128) — champion path for qkv.
// ---------------------------------------------------------------------------
template<bool HAS_BIAS, bool GELU, bool RESID, bool QSCALE, int OMODE>
__global__ __launch_bounds__(256)
void gemm_mfma(const unsigned short* __restrict__ A,
               const unsigned short* __restrict__ W,
               const float* __restrict__ bias,
               const unsigned short* __restrict__ resid,
               void* __restrict__ Cv,
               int Nn, int Kk)
{
    __shared__ unsigned short As[2][128 * 64];
    __shared__ unsigned short Bs[2][128 * 64];

    int t = threadIdx.x;
    int w = t >> 6, lane = t & 63;
    int wr = w >> 1, wc = w & 1;
    int l15 = lane & 15, l4 = lane >> 4;
    int m0 = blockIdx.y * 128, n0 = blockIdx.x * 128;

    int lrow = lane >> 3;
    int segp = (lane & 7) ^ lrow;

    float4v acc[4][4];
    #pragma unroll
    for (int i = 0; i < 4; i++)
        #pragma unroll
        for (int j = 0; j < 4; j++)
            acc[i][j] = (float4v){0.f, 0.f, 0.f, 0.f};

    #define STAGE(buf, k0) do {                                                   \
        _Pragma("unroll")                                                         \
        for (int i_ = 0; i_ < 4; i_++) {                                          \
            int r_ = i_ * 32 + w * 8 + lrow;                                      \
            __builtin_amdgcn_global_load_lds(                                     \
                (glb_u32*)(A + (size_t)(m0 + r_) * Kk + (k0) + segp * 8),         \
                (lds_u32*)(As[buf] + i_ * 2048 + w * 512), 16, 0, 0);             \
            __builtin_amdgcn_global_load_lds(                                     \
                (glb_u32*)(W + (size_t)(n0 + r_) * Kk + (k0) + segp * 8),         \
                (lds_u32*)(Bs[buf] + i_ * 2048 + w * 512), 16, 0, 0);             \
        } } while (0)

    int nk = Kk >> 6;
    STAGE(0, 0);
    for (int kt = 0; kt < nk; kt++) {
        int cur = kt & 1;
        if (kt + 1 < nk) {
            STAGE(cur ^ 1, (kt + 1) << 6);
            __builtin_amdgcn_sched_barrier(0);
            asm volatile("s_waitcnt vmcnt(8)");
            __builtin_amdgcn_sched_barrier(0);
        } else {
            __builtin_amdgcn_sched_barrier(0);
            asm volatile("s_waitcnt vmcnt(0)");
            __builtin_amdgcn_sched_barrier(0);
        }
        __builtin_amdgcn_s_barrier();

        const char* asb = (const char*)As[cur];
        const char* bsb = (const char*)Bs[cur];
        #pragma unroll
        for (int kc = 0; kc < 2; kc++) {
            short8v af[4], bfr[4];
            #pragma unroll
            for (int mf = 0; mf < 4; mf++) {
                int row = wr * 64 + mf * 16 + l15;
                int off = (row * 128 + kc * 64 + l4 * 16) ^ ((row & 7) << 4);
                af[mf] = *reinterpret_cast<const short8v*>(asb + off);
            }
            #pragma unroll
            for (int nf = 0; nf < 4; nf++) {
                int row = wc * 64 + nf * 16 + l15;
                int off = (row * 128 + kc * 64 + l4 * 16) ^ ((row & 7) << 4);
                bfr[nf] = *reinterpret_cast<const short8v*>(bsb + off);
            }
            #pragma unroll
            for (int mf = 0; mf < 4; mf++)
                #pragma unroll
                for (int nf = 0; nf < 4; nf++)
                    acc[mf][nf] = __builtin_amdgcn_mfma_f32_16x16x32_bf16(
                        af[mf], bfr[nf], acc[mf][nf], 0, 0, 0);
        }
        __builtin_amdgcn_s_barrier();
    }
    #undef STAGE

    #pragma unroll
    for (int mf = 0; mf < 4; mf++)
        #pragma unroll
        for (int nf = 0; nf < 4; nf++)
            #pragma unroll
            for (int r = 0; r < 4; r++) {
                int m = m0 + wr * 64 + mf * 16 + l4 * 4 + r;
                int n = n0 + wc * 64 + nf * 16 + l15;
                if (n < Nn) {
                    float v = acc[mf][nf][r];
                    if (HAS_BIAS) v += bias[n];
                    if (GELU)     v = gelu_tanh(v);
                    if (RESID)    v += bf2f(resid[(size_t)m * Nn + n]);
                    if (QSCALE && n < DD) v *= C8;
                    if (OMODE == 1)
                        ((unsigned short*)Cv)[(size_t)m * Nn + n] = f2bf(v);
                    else
                        ((float*)Cv)[(size_t)m * Nn + n] = v;
                }
            }
}

// ---------------------------------------------------------------------------
// Kernel 3c: MT=64 GEMM with 3-buffer ring + stage-ahead-2 (ao/ffn2/logits).
// ---------------------------------------------------------------------------
template<bool HAS_BIAS, bool GELU, bool RESID, int OMODE>
__global__ __launch_bounds__(128)
void gemm_mfma64_d3(const unsigned short* __restrict__ A,
                    const unsigned short* __restrict__ W,
                    const float* __restrict__ bias,
                    const unsigned short* __restrict__ resid,
                    void* __restrict__ Cv,
                    int Nn, int Kk)
{
    __shared__ unsigned short As[3][64 * 64];    // 8 KB each
    __shared__ unsigned short Bs[3][128 * 64];   // 16 KB each

    int t = threadIdx.x;
    int w = t >> 6, lane = t & 63;               // w in [0,2)
    int wc = w;                                  // wave n-half; wr = 0
    int l15 = lane & 15, l4 = lane >> 4;
    int m0 = blockIdx.y * 64, n0 = blockIdx.x * 128;

    int lrow = lane >> 3;
    int segp = (lane & 7) ^ lrow;

    float4v acc[4][4];
    #pragma unroll
    for (int i = 0; i < 4; i++)
        #pragma unroll
        for (int j = 0; j < 4; j++)
            acc[i][j] = (float4v){0.f, 0.f, 0.f, 0.f};

    #define STAGE64(buf, k0) do {                                                 \
        _Pragma("unroll")                                                         \
        for (int i_ = 0; i_ < 4; i_++) {                                          \
            int r_ = i_ * 16 + w * 8 + lrow;                                      \
            __builtin_amdgcn_global_load_lds(                                     \
                (glb_u32*)(A + (size_t)(m0 + r_) * Kk + (k0) + segp * 8),         \
                (lds_u32*)(As[buf] + i_ * 1024 + w * 512), 16, 0, 0);             \
        }                                                                         \
        _Pragma("unroll")                                                         \
        for (int i_ = 0; i_ < 8; i_++) {                                          \
            int r_ = i_ * 16 + w * 8 + lrow;                                      \
            __builtin_amdgcn_global_load_lds(                                     \
                (glb_u32*)(W + (size_t)(n0 + r_) * Kk + (k0) + segp * 8),         \
                (lds_u32*)(Bs[buf] + i_ * 1024 + w * 512), 16, 0, 0);             \
        } } while (0)

    int nk = Kk >> 6;                            // >= 8 for all uses
    STAGE64(0, 0);
    STAGE64(1, 64);

    int cur = 0;
    for (int kt = 0; kt < nk; kt++) {
        if (kt + 2 < nk) {
            int sb = cur + 2; if (sb >= 3) sb -= 3;
            STAGE64(sb, (kt + 2) << 6);
        }
        __builtin_amdgcn_sched_barrier(0);
        int rem = nk - 1 - kt;
        if (rem >= 2)      asm volatile("s_waitcnt vmcnt(24)");
        else if (rem == 1) asm volatile("s_waitcnt vmcnt(12)");
        else               asm volatile("s_waitcnt vmcnt(0)");
        __builtin_amdgcn_sched_barrier(0);
        __builtin_amdgcn_s_barrier();            // publish tile kt

        const char* asb = (const char*)As[cur];
        const char* bsb = (const char*)Bs[cur];
        #pragma unroll
        for (int kc = 0; kc < 2; kc++) {
            short8v af[4], bfr[4];
            #pragma unroll
            for (int mf = 0; mf < 4; mf++) {
                int row = mf * 16 + l15;
                int off = (row * 128 + kc * 64 + l4 * 16) ^ ((row & 7) << 4);
                af[mf] = *reinterpret_cast<const short8v*>(asb + off);
            }
            #pragma unroll
            for (int nf = 0; nf < 4; nf++) {
                int row = wc * 64 + nf * 16 + l15;
                int off = (row * 128 + kc * 64 + l4 * 16) ^ ((row & 7) << 4);
                bfr[nf] = *reinterpret_cast<const short8v*>(bsb + off);
            }
            __builtin_amdgcn_s_setprio(1);
            #pragma unroll
            for (int mf = 0; mf < 4; mf++)
                #pragma unroll
                for (int nf = 0; nf < 4; nf++)
                    acc[mf][nf] = __builtin_amdgcn_mfma_f32_16x16x32_bf16(
                        af[mf], bfr[nf], acc[mf][nf], 0, 0, 0);
            __builtin_amdgcn_s_setprio(0);
        }
        __builtin_amdgcn_s_barrier();            // fence readers before overwrite
        cur = cur + 1; if (cur >= 3) cur -= 3;
    }
    #undef STAGE64

    #pragma unroll
    for (int mf = 0; mf < 4; mf++)
        #pragma unroll
        for (int nf = 0; nf < 4; nf++)
            #pragma unroll
            for (int r = 0; r < 4; r++) {
                int m = m0 + mf * 16 + l4 * 4 + r;
                int n = n0 + wc * 64 + nf * 16 + l15;
                if (n < Nn) {
                    float v = acc[mf][nf][r];
                    if (HAS_BIAS) v += bias[n];
                    if (GELU)     v = gelu_tanh(v);
                    if (RESID)    v += bf2f(resid[(size_t)m * Nn + n]);
                    if (OMODE == 1)
                        ((unsigned short*)Cv)[(size_t)m * Nn + n] = f2bf(v);
                    else
                        ((float*)Cv)[(size_t)m * Nn + n] = v;
                }
            }
}

// ---------------------------------------------------------------------------
// Kernel 3b: deep-pipelined 256x256 MFMA GEMM (ffn1) — unchanged from R17.
// ---------------------------------------------------------------------------
__global__ __launch_bounds__(512, 1)
void gemm_mfma_256(const unsigned short* __restrict__ A,
                   const unsigned short* __restrict__ W,
                   const float* __restrict__ bias,
                   unsigned short* __restrict__ C,
                   int Nn, int Kk)
{
    __shared__ unsigned short As2[2][256 * 64];   // 64 KB
    __shared__ unsigned short Bs2[2][256 * 64];   // 64 KB

    int t = threadIdx.x;
    int w = t >> 6, lane = t & 63;                // w in [0,8)
    int wr = w >> 2, wc = w & 3;                  // 2M x 4N wave grid
    int l15 = lane & 15, l4 = lane >> 4;

    int flat = blockIdx.x;
    int bx = flat >> 5, by = flat & 31;           // flat%8 == by%8 (XCD co-locate)
    int m0 = by * 256, n0 = bx * 256;

    int lrow8 = lane >> 3;
    int grow = w * 8 + lrow8;
    int segp = (lane & 7) ^ lrow8;

    float4v acc[8][4];
    #pragma unroll
    for (int i = 0; i < 8; i++)
        #pragma unroll
        for (int j = 0; j < 4; j++)
            acc[i][j] = (float4v){0.f, 0.f, 0.f, 0.f};

    #define STG_HALF(P, RB, K0, L) do {                                           \
        __builtin_amdgcn_global_load_lds(                                         \
            (glb_u32*)(P + (size_t)((RB) + grow) * Kk + (K0) + segp * 8),         \
            (lds_u32*)((L) + w * 512), 16, 0, 0);                                 \
        __builtin_amdgcn_global_load_lds(                                         \
            (glb_u32*)(P + (size_t)((RB) + 64 + grow) * Kk + (K0) + segp * 8),    \
            (lds_u32*)((L) + 4096 + w * 512), 16, 0, 0);                          \
    } while (0)

    #define STG_TILE(buf, K0) do {                                               \
        STG_HALF(A, m0,       (K0), As2[buf]);                                   \
        STG_HALF(A, m0 + 128, (K0), As2[buf] + 8192);                            \
        STG_HALF(W, n0,       (K0), Bs2[buf]);                                   \
        STG_HALF(W, n0 + 128, (K0), Bs2[buf] + 8192);                            \
    } while (0)

    int nk = Kk >> 6;
    STG_TILE(0, 0);

    for (int kt = 0; kt < nk; kt++) {
        int cur = kt & 1;
        if (kt + 1 < nk) {
            STG_TILE(cur ^ 1, (kt + 1) << 6);
            __builtin_amdgcn_sched_barrier(0);
            asm volatile("s_waitcnt vmcnt(8)");
            __builtin_amdgcn_sched_barrier(0);
        } else {
            __builtin_amdgcn_sched_barrier(0);
            asm volatile("s_waitcnt vmcnt(0)");
            __builtin_amdgcn_sched_barrier(0);
        }
        __builtin_amdgcn_s_barrier();

        const char* asb = (const char*)As2[cur];
        const char* bsb = (const char*)Bs2[cur];
        short8v af[4], bfr[4];

        #pragma unroll
        for (int ph = 0; ph < 4; ph++) {
            int kc = ph >> 1;
            int mh = ph & 1;
            if (mh == 0) {
                #pragma unroll
                for (int nf = 0; nf < 4; nf++) {
                    int row = wc * 64 + nf * 16 + l15;
                    int off = (row * 128 + kc * 64 + l4 * 16) ^ ((row & 7) << 4);
                    bfr[nf] = *reinterpret_cast<const short8v*>(bsb + off);
                }
            }
            #pragma unroll
            for (int mf = 0; mf < 4; mf++) {
                int row = wr * 128 + (mh * 4 + mf) * 16 + l15;
                int off = (row * 128 + kc * 64 + l4 * 16) ^ ((row & 7) << 4);
                af[mf] = *reinterpret_cast<const short8v*>(asb + off);
            }
            __builtin_amdgcn_s_setprio(1);
            #pragma unroll
            for (int mf = 0; mf < 4; mf++)
                #pragma unroll
                for (int nf = 0; nf < 4; nf++)
                    acc[mh * 4 + mf][nf] = __builtin_amdgcn_mfma_f32_16x16x32_bf16(
                        af[mf], bfr[nf], acc[mh * 4 + mf][nf], 0, 0, 0);
            __builtin_amdgcn_s_setprio(0);
        }
        __builtin_amdgcn_s_barrier();
    }
    #undef STG_TILE
    #undef STG_HALF

    #pragma unroll
    for (int mf = 0; mf < 8; mf++)
        #pragma unroll
        for (int nf = 0; nf < 4; nf++)
            #pragma unroll
            for (int r = 0; r < 4; r++) {
                int m = m0 + wr * 128 + mf * 16 + l4 * 4 + r;
                int n = n0 + wc * 64 + nf * 16 + l15;
                float v = acc[mf][nf][r] + bias[n];
                v = gelu_tanh(v);
                C[(size_t)m * Nn + n] = f2bf(v);
            }
}

// ---------------------------------------------------------------------------
// Kernel 4: MFMA flash attention. R18 champion + WAVE-STAGGERED half order:
// odd waves process the two 64-key halves in reverse (hf ^ (w&1)). Both
// halves are in the same published buffer so order is correctness-neutral,
// but at any instant half the waves run QK^T/PV (MFMA pipe) while the other
// half runs the exp section (VALU pipe) -> cross-wave pipe overlap (m114)
// instead of lockstep alternation.
// ---------------------------------------------------------------------------
__global__ __launch_bounds__(512, 2)
void attn_mfma(const unsigned short* __restrict__ qkv, unsigned short* __restrict__ o)
{
    __shared__ unsigned short Kl[2][128 * 64];
    __shared__ unsigned short Vs[2][128 * 64];
    __shared__ float Scl[8][16];

    int t = threadIdx.x, w = t >> 6, lane = t & 63;
    int l15 = lane & 15, l4 = lane >> 4;

    int flat = blockIdx.x;
    int swz = (flat & 7) * 64 + (flat >> 3);
    int qt = swz & 15, hh = (swz >> 4) & 7, b = swz >> 7;

    int q0 = qt * 128 + w * 16;
    const int RS = 3 * DD; // 1536

    short8v qf[2];
    #pragma unroll
    for (int dh = 0; dh < 2; dh++) {
        size_t addr = (size_t)(b * LL + q0 + l15) * RS + hh * HDIM + dh * 32 + l4 * 8;
        qf[dh] = *reinterpret_cast<const short8v*>(qkv + addr);
    }

    float4v o_acc[4];
    #pragma unroll
    for (int dt = 0; dt < 4; dt++) o_acc[dt] = (float4v){0.f, 0.f, 0.f, 0.f};
    float l_run = 0.f;

    int lrow8 = lane >> 3;
    int ksegp = (lane & 7) ^ lrow8;
    int rho = w * 8 + lrow8;
    int kappa = ((rho >> 5) << 5) | (((rho >> 4) & 1) << 2)
              | (((rho >> 2) & 3) << 3) | (rho & 3);
    int vrow = ((t >> 5) << 2) | ((t >> 1) & 3);
    int vseg = (((t >> 3) & 3) << 1) | (t & 1);
    const unsigned short* kgl = qkv + (size_t)(b * LL + kappa) * RS
                              + hh * HDIM + DD + ksegp * 8;
    const unsigned short* vgl = qkv + (size_t)(b * LL + vrow) * RS
                              + hh * HDIM + 2 * DD + vseg * 8;
    const int halfstep = 64 * RS;
    const int step = 128 * RS;

    #define ASTAGE(buf) do {                                                      \
        __builtin_amdgcn_global_load_lds((glb_u32*)kgl,                           \
            (lds_u32*)(Kl[buf] + w * 512), 16, 0, 0);                             \
        __builtin_amdgcn_global_load_lds((glb_u32*)(kgl + halfstep),              \
            (lds_u32*)(Kl[buf] + 4096 + w * 512), 16, 0, 0);                      \
        __builtin_amdgcn_global_load_lds((glb_u32*)vgl,                           \
            (lds_u32*)(Vs[buf] + w * 512), 16, 0, 0);                             \
        __builtin_amdgcn_global_load_lds((glb_u32*)(vgl + halfstep),              \
            (lds_u32*)(Vs[buf] + 4096 + w * 512), 16, 0, 0);                      \
        kgl += step; vgl += step; } while (0)

    unsigned vtrbase = lds_addr(Vs) + ((lane >> 4) << 10)
                     + (((lane >> 2) & 3) << 5) + ((lane & 3) << 3);

    ASTAGE(0);
    asm volatile("s_waitcnt vmcnt(0)");
    __syncthreads();

    int hstag = w & 1;   // odd waves reverse half order (role-split stagger)

    for (int kb = 0; kb < LL / 128; kb++) {
        int cur = kb & 1;
        if (kb + 1 < LL / 128) ASTAGE(cur ^ 1);

        #pragma unroll
        for (int hfi = 0; hfi < 2; hfi++) {
            int hf = hfi ^ hstag;
            const char* klc = (const char*)Kl[cur] + hf * 8192;
            unsigned vb = vtrbase + cur * 16384 + hf * 8192;

            float4v s_acc[4];
            __builtin_amdgcn_s_setprio(1);
            #pragma unroll
            for (int nt = 0; nt < 4; nt++) {
                s_acc[nt] = (float4v){0.f, 0.f, 0.f, 0.f};
                #pragma unroll
                for (int dh = 0; dh < 2; dh++) {
                    int row = nt * 16 + l15;
                    int off = (row * 128 + dh * 64 + l4 * 16) ^ ((row & 7) << 4);
                    short8v kf = *reinterpret_cast<const short8v*>(klc + off);
                    s_acc[nt] = __builtin_amdgcn_mfma_f32_16x16x32_bf16(kf, qf[dh], s_acc[nt], 0, 0, 0);
                }
            }
            __builtin_amdgcn_s_setprio(0);

            unsigned long long a0, a1, a2, a3, a4, a5, a6, a7;
            unsigned long long b0, b1, b2, b3, b4, b5, b6, b7;
            unsigned ab0 = vb, ab1 = vb + 4096;
            asm volatile("ds_read_b64_tr_b16 %0, %1" : "=v"(a0) : "v"(ab0));
            asm volatile("ds_read_b64_tr_b16 %0, %1" : "=v"(a1) : "v"(ab0 + 512));
            asm volatile("ds_read_b64_tr_b16 %0, %1" : "=v"(a2) : "v"(ab0 + 128));
            asm volatile("ds_read_b64_tr_b16 %0, %1" : "=v"(a3) : "v"(ab0 + 640));
            asm volatile("ds_read_b64_tr_b16 %0, %1" : "=v"(a4) : "v"(ab0 + 256));
            asm volatile("ds_read_b64_tr_b16 %0, %1" : "=v"(a5) : "v"(ab0 + 768));
            asm volatile("ds_read_b64_tr_b16 %0, %1" : "=v"(a6) : "v"(ab0 + 384));
            asm volatile("ds_read_b64_tr_b16 %0, %1" : "=v"(a7) : "v"(ab0 + 896));
            asm volatile("ds_read_b64_tr_b16 %0, %1" : "=v"(b0) : "v"(ab1));
            asm volatile("ds_read_b64_tr_b16 %0, %1" : "=v"(b1) : "v"(ab1 + 512));
            asm volatile("ds_read_b64_tr_b16 %0, %1" : "=v"(b2) : "v"(ab1 + 128));
            asm volatile("ds_read_b64_tr_b16 %0, %1" : "=v"(b3) : "v"(ab1 + 640));
            asm volatile("ds_read_b64_tr_b16 %0, %1" : "=v"(b4) : "v"(ab1 + 256));
            asm volatile("ds_read_b64_tr_b16 %0, %1" : "=v"(b5) : "v"(ab1 + 768));
            asm volatile("ds_read_b64_tr_b16 %0, %1" : "=v"(b6) : "v"(ab1 + 384));
            asm volatile("ds_read_b64_tr_b16 %0, %1" : "=v"(b7) : "v"(ab1 + 896));

            union { unsigned u[4]; short8v v; } pf0u, pf1u;
            float ps;
            {
                float p0 = __builtin_amdgcn_exp2f(s_acc[0][0]);
                float p1 = __builtin_amdgcn_exp2f(s_acc[0][1]);
                float p2 = __builtin_amdgcn_exp2f(s_acc[0][2]);
                float p3 = __builtin_amdgcn_exp2f(s_acc[0][3]);
                float p4 = __builtin_amdgcn_exp2f(s_acc[1][0]);
                float p5 = __builtin_amdgcn_exp2f(s_acc[1][1]);
                float p6 = __builtin_amdgcn_exp2f(s_acc[1][2]);
                float p7 = __builtin_amdgcn_exp2f(s_acc[1][3]);
                asm("v_cvt_pk_bf16_f32 %0, %1, %2" : "=v"(pf0u.u[0]) : "v"(p0), "v"(p1));
                asm("v_cvt_pk_bf16_f32 %0, %1, %2" : "=v"(pf0u.u[1]) : "v"(p2), "v"(p3));
                asm("v_cvt_pk_bf16_f32 %0, %1, %2" : "=v"(pf0u.u[2]) : "v"(p4), "v"(p5));
                asm("v_cvt_pk_bf16_f32 %0, %1, %2" : "=v"(pf0u.u[3]) : "v"(p6), "v"(p7));
                ps = ((p0 + p1) + (p2 + p3)) + ((p4 + p5) + (p6 + p7));
            }
            {
                float p0 = __builtin_amdgcn_exp2f(s_acc[2][0]);
                float p1 = __builtin_amdgcn_exp2f(s_acc[2][1]);
                float p2 = __builtin_amdgcn_exp2f(s_acc[2][2]);
                float p3 = __builtin_amdgcn_exp2f(s_acc[2][3]);
                float p4 = __builtin_amdgcn_exp2f(s_acc[3][0]);
                float p5 = __builtin_amdgcn_exp2f(s_acc[3][1]);
                float p6 = __builtin_amdgcn_exp2f(s_acc[3][2]);
                float p7 = __builtin_amdgcn_exp2f(s_acc[3][3]);
                asm("v_cvt_pk_bf16_f32 %0, %1, %2" : "=v"(pf1u.u[0]) : "v"(p0), "v"(p1));
                asm("v_cvt_pk_bf16_f32 %0, %1, %2" : "=v"(pf1u.u[1]) : "v"(p2), "v"(p3));
                asm("v_cvt_pk_bf16_f32 %0, %1, %2" : "=v"(pf1u.u[2]) : "v"(p4), "v"(p5));
                asm("v_cvt_pk_bf16_f32 %0, %1, %2" : "=v"(pf1u.u[3]) : "v"(p6), "v"(p7));
                ps += ((p0 + p1) + (p2 + p3)) + ((p4 + p5) + (p6 + p7));
            }
            l_run += ps;

            union { unsigned long long q[2]; short8v v; } u0, u1, u2, u3;
            asm volatile("s_waitcnt lgkmcnt(8)");
            __builtin_amdgcn_sched_barrier(0);
            __builtin_amdgcn_s_setprio(1);
            u0.q[0] = a0; u0.q[1] = a1;
            u1.q[0] = a2; u1.q[1] = a3;
            o_acc[0] = __builtin_amdgcn_mfma_f32_16x16x32_bf16(pf0u.v, u0.v, o_acc[0], 0, 0, 0);
            o_acc[1] = __builtin_amdgcn_mfma_f32_16x16x32_bf16(pf0u.v, u1.v, o_acc[1], 0, 0, 0);
            asm volatile("s_waitcnt lgkmcnt(4)");
            __builtin_amdgcn_sched_barrier(0);
            u2.q[0] = a4; u2.q[1] = a5;
            u3.q[0] = a6; u3.q[1] = a7;
            o_acc[2] = __builtin_amdgcn_mfma_f32_16x16x32_bf16(pf0u.v, u2.v, o_acc[2], 0, 0, 0);
            o_acc[3] = __builtin_amdgcn_mfma_f32_16x16x32_bf16(pf0u.v, u3.v, o_acc[3], 0, 0, 0);
            asm volatile("s_waitcnt lgkmcnt(0)");
            __builtin_amdgcn_sched_barrier(0);
            u0.q[0] = b0; u0.q[1] = b1;
            u1.q[0] = b2; u1.q[1] = b3;
            u2.q[0] = b4; u2.q[1] = b5;
            u3.q[0] = b6; u3.q[1] = b7;
            o_acc[0] = __builtin_amdgcn_mfma_f32_16x16x32_bf16(pf1u.v, u0.v, o_acc[0], 0, 0, 0);
            o_acc[1] = __builtin_amdgcn_mfma_f32_16x16x32_bf16(pf1u.v, u1.v, o_acc[1], 0, 0, 0);
            o_acc[2] = __builtin_amdgcn_mfma_f32_16x16x32_bf16(pf1u.v, u2.v, o_acc[2], 0, 0, 0);
            o_acc[3] = __builtin_amdgcn_mfma_f32_16x16x32_bf16(pf1u.v, u3.v, o_acc[3], 0, 0, 0);
            __builtin_amdgcn_s_setprio(0);
        }

        asm volatile("s_waitcnt vmcnt(0)");
        __syncthreads();
    }
    #undef ASTAGE

    float lt = l_run;
    lt += __shfl_xor(lt, 16);
    lt += __shfl_xor(lt, 32);
    if (l4 == 0) Scl[w][l15] = 1.f / lt;
    float4 iv = *reinterpret_cast<const float4*>(&Scl[w][l4 * 4]);
    float invs[4] = {iv.x, iv.y, iv.z, iv.w};
    #pragma unroll
    for (int r = 0; r < 4; r++) {
        int qg = q0 + l4 * 4 + r;
        #pragma unroll
        for (int dt = 0; dt < 4; dt++) {
            o[(size_t)(b * LL + qg) * DD + hh * HDIM + dt * 16 + l15] =
                f2bf(o_acc[dt][r] * invs[r]);
        }
    }
}

// ---------------------------------------------------------------------------
// Driver
// ---------------------------------------------------------------------------
extern "C" void kernel_launch(void* const* d_in, const int* in_sizes, int n_in,
                              void* d_out, int out_size, void* d_ws, size_t ws_size,
                              hipStream_t stream)
{
    const float* emb    = (const float*)d_in[0];
    const float* ent_w  = (const float*)d_in[1];
    const float* ent_b  = (const float*)d_in[2];
    const float* qkv_w  = (const float*)d_in[3];
    const float* qkv_b  = (const float*)d_in[4];
    const float* ao_w   = (const float*)d_in[5];
    const float* ao_b   = (const float*)d_in[6];
    const float* ln1_s  = (const float*)d_in[7];
    const float* ln1_b  = (const float*)d_in[8];
    const float* ln2_s  = (const float*)d_in[9];
    const float* ln2_b  = (const float*)d_in[10];
    const float* ff1_w  = (const float*)d_in[11];
    const float* ff1_b  = (const float*)d_in[12];
    const float* ff2_w  = (const float*)d_in[13];
    const float* ff2_b  = (const float*)d_in[14];
    const float* out_w  = (const float*)d_in[15];
    const int*   x      = (const int*)d_in[16];
    // d_in[17] = patch_lengths : dead code in the reference

    float* out = (float*)d_out;

    const int NQW = NLAYER * 3 * DD * DD;
    const int NAW = NLAYER * DD * DD;
    const int NF1 = NLAYER * 4 * DD * DD;
    const int NF2 = NLAYER * DD * 4 * DD;

    char* p = (char*)d_ws;
    unsigned short* wq  = (unsigned short*)p; p += (size_t)NQW * 2;
    unsigned short* wa  = (unsigned short*)p; p += (size_t)NAW * 2;
    unsigned short* w1  = (unsigned short*)p; p += (size_t)NF1 * 2;
    unsigned short* w2  = (unsigned short*)p; p += (size_t)NF2 * 2;
    unsigned short* wob = (unsigned short*)p; p += (size_t)VPAD * DD * 2;
    unsigned short* h   = (unsigned short*)p; p += (size_t)MM * DD * 2;   // bf16 residual
    unsigned short* gb  = (unsigned short*)p; p += (size_t)MM * DD * 2;
    unsigned short* ob  = (unsigned short*)p; p += (size_t)MM * DD * 2;
    unsigned short* bb  = (unsigned short*)p; p += (size_t)MM * 4 * DD * 2; // qkv / ffn

    dim3 blk(256);

    cvt_all_kernel<<<E4 / 1024, blk, 0, stream>>>(qkv_w, ao_w, ff1_w, ff2_w, out_w, wq);

    embed_ln_kernel<<<MM / 4, blk, 0, stream>>>(x, emb, ent_w, ent_b,
                                                ln1_s, ln1_b, h, gb);

    for (int layer = 0; layer < NLAYER; layer++) {
        const unsigned short* qw = wq + (size_t)layer * 3 * DD * DD;
        const unsigned short* aw = wa + (size_t)layer * DD * DD;
        const unsigned short* f1 = w1 + (size_t)layer * 4 * DD * DD;
        const unsigned short* f2 = w2 + (size_t)layer * DD * 4 * DD;
        const float* qb  = qkv_b + (size_t)layer * 3 * DD;
        const float* ab  = ao_b  + (size_t)layer * DD;
        const float* l1s = ln1_s + (size_t)layer * DD;
        const float* l1b = ln1_b + (size_t)layer * DD;
        const float* l2s = ln2_s + (size_t)layer * DD;
        const float* l2b = ln2_b + (size_t)layer * DD;
        const float* f1b = ff1_b + (size_t)layer * 4 * DD;
        const float* f2b = ff2_b + (size_t)layer * DD;

        // LN1 (layer 0 fused into embed_ln_kernel)
        if (layer > 0)
            ln_kernel<<<MM / 4, blk, 0, stream>>>(h, l1s, l1b, gb);

        // qkv = gb @ qw^T + qb -> bb (bf16) [MM,1536], Q cols pre-scaled by C8
        {
            dim3 grid((3 * DD) / 128, MM / 128);
            gemm_mfma<true, false, false, true, 1><<<grid, 256, 0, stream>>>(
                gb, qw, qb, nullptr, bb, 3 * DD, DD);
        }

        // attention: bb -> ob (bf16)
        attn_mfma<<<512, 512, 0, stream>>>(bb, ob);

        // h = h + ob @ aw^T + ab  (bf16 out; MT=64 3-buffer deep pipe)
        {
            dim3 grid(DD / 128, MM / 64);
            gemm_mfma64_d3<true, false, true, 1><<<grid, 128, 0, stream>>>(
                ob, aw, ab, h, h, DD, DD);
        }

        // LN2: h -> gb
        ln_kernel<<<MM / 4, blk, 0, stream>>>(h, l2s, l2b, gb);

        // ffn1: bb = gelu(gb @ f1^T + f1b) (bf16) [MM,2048] -- deep-pipelined 256^2
        gemm_mfma_256<<<(MM / 256) * ((4 * DD) / 256), 512, 0, stream>>>(
            gb, f1, f1b, bb, 4 * DD, DD);

        // ffn2: h = h + bb @ f2^T + f2b  (bf16 out; MT=64 3-buffer deep pipe)
        {
            dim3 grid(DD / 128, MM / 64);
            gemm_mfma64_d3<true, false, true, 1><<<grid, 128, 0, stream>>>(
                bb, f2, f2b, h, h, DD, 4 * DD);
        }
    }

    // logits = h @ wob^T [MM, 258] via MFMA on padded weight (MT=64 3-buffer)
    {
        dim3 grid(VPAD / 128, MM / 64);
        gemm_mfma64_d3<false, false, false, 0><<<grid, 128, 0, stream>>>(
            h, wob, nullptr, nullptr, out, VV, DD);
    }
}

// Round 20
// 669.510 us; speedup vs baseline: 1.0081x; 1.0081x over previous
//
#include <hip/hip_runtime.h>
#include <hip/hip_bf16.h>
#include <math.h>

// Problem constants
#define BB 4
#define LL 2048
#define DD 512
#define HH 8
#define NLAYER 4
#define VV 258
#define WW 8
#define HDIM 64
#define MM (BB * LL)   // 8192 rows
#define VPAD 384       // logits weight rows padded to tile multiple

// 0.125 * log2(e): QK^T scale, folded into Q at the qkv-GEMM epilogue
#define C8 0.18033688f

typedef __attribute__((ext_vector_type(8))) short short8v;
typedef __attribute__((ext_vector_type(4))) float float4v;

typedef __attribute__((address_space(3))) unsigned int lds_u32;
typedef const __attribute__((address_space(1))) unsigned int glb_u32;

__device__ __forceinline__ unsigned short f2bf(float x) {
    unsigned int u = __float_as_uint(x);
    unsigned int r = (u + 0x7fffu + ((u >> 16) & 1u)) >> 16;
    return (unsigned short)r;
}
__device__ __forceinline__ float bf2f(unsigned short u) {
    return __uint_as_float((unsigned)u << 16);
}

__device__ __forceinline__ unsigned lds_addr(const void* p) {
    return (unsigned)(size_t)(__attribute__((address_space(3))) const void*)p;
}

__device__ __forceinline__ float gelu_tanh(float v) {
    float a = 0.044715f * v * v;
    float u = fminf(fmaf(a, v, v) * 2.3022077f, 80.f);
    float e = __builtin_amdgcn_exp2f(u);
    return v * e * __builtin_amdgcn_rcpf(e + 1.f);
}

// ---------------------------------------------------------------------------
// Fused weight conversion: all four layer-weight arrays + padded out_w.
// ---------------------------------------------------------------------------
#define E0 (NLAYER * 3 * DD * DD)          // 3,145,728
#define E1 (E0 + NLAYER * DD * DD)         // 4,194,304
#define E2 (E1 + NLAYER * 4 * DD * DD)     // 8,388,608
#define E3 (E2 + NLAYER * 4 * DD * DD)     // 12,582,912
#define E4 (E3 + VPAD * DD)                // 12,779,520

__global__ __launch_bounds__(256)
void cvt_all_kernel(const float* __restrict__ qkv_w, const float* __restrict__ ao_w,
                    const float* __restrict__ ff1_w, const float* __restrict__ ff2_w,
                    const float* __restrict__ out_w, unsigned short* __restrict__ dst)
{
    int i = (blockIdx.x * 256 + threadIdx.x) * 4;
    float4 v;
    if (i < E0)      v = *reinterpret_cast<const float4*>(qkv_w + i);
    else if (i < E1) v = *reinterpret_cast<const float4*>(ao_w + (i - E0));
    else if (i < E2) v = *reinterpret_cast<const float4*>(ff1_w + (i - E1));
    else if (i < E3) v = *reinterpret_cast<const float4*>(ff2_w + (i - E2));
    else {
        int idx = i - E3;
        if ((idx >> 9) < VV) v = *reinterpret_cast<const float4*>(out_w + idx);
        else                 v = (float4){0.f, 0.f, 0.f, 0.f};
    }
    uint2 pk;
    pk.x = (unsigned)f2bf(v.x) | ((unsigned)f2bf(v.y) << 16);
    pk.y = (unsigned)f2bf(v.z) | ((unsigned)f2bf(v.w) << 16);
    *reinterpret_cast<uint2*>(dst + i) = pk;
}

// ---------------------------------------------------------------------------
// Kernel 1: fused token embedding + entropy feature + LN1(layer 0)
// ---------------------------------------------------------------------------
__global__ __launch_bounds__(256)
void embed_ln_kernel(const int* __restrict__ x,
                     const float* __restrict__ emb,
                     const float* __restrict__ ent_w,
                     const float* __restrict__ ent_b,
                     const float* __restrict__ ln_s,
                     const float* __restrict__ ln_b,
                     unsigned short* __restrict__ h,
                     unsigned short* __restrict__ g)
{
    int w = threadIdx.x >> 6, lane = threadIdx.x & 63;
    int row = blockIdx.x * 4 + w;
    int b = row / LL, l = row % LL;

    float ent = 0.f;
    if (l <= LL - WW) {
        int win[WW];
        #pragma unroll
        for (int i = 0; i < WW; i++) win[i] = x[b * LL + l + i];
        float s = 0.f;
        #pragma unroll
        for (int i = 0; i < WW; i++) {
            if (win[i] < 256) {
                int c = 0;
                #pragma unroll
                for (int j = 0; j < WW; j++) c += (win[j] == win[i]) ? 1 : 0;
                s += log2f((float)c * 0.125f + 1e-10f);
            }
        }
        ent = -s * 0.125f;
    }

    int tok = x[row];
    const float* erow = emb + (size_t)tok * DD + lane * 8;
    float v[8], ew[8], eb[8];
    *reinterpret_cast<float4*>(v)      = *reinterpret_cast<const float4*>(erow);
    *reinterpret_cast<float4*>(v + 4)  = *reinterpret_cast<const float4*>(erow + 4);
    *reinterpret_cast<float4*>(ew)     = *reinterpret_cast<const float4*>(ent_w + lane * 8);
    *reinterpret_cast<float4*>(ew + 4) = *reinterpret_cast<const float4*>(ent_w + lane * 8 + 4);
    *reinterpret_cast<float4*>(eb)     = *reinterpret_cast<const float4*>(ent_b + lane * 8);
    *reinterpret_cast<float4*>(eb + 4) = *reinterpret_cast<const float4*>(ent_b + lane * 8 + 4);

    float sum = 0.f, sq = 0.f;
    #pragma unroll
    for (int i = 0; i < 8; i++) {
        v[i] = v[i] + ent * ew[i] + eb[i];
        sum += v[i]; sq += v[i] * v[i];
    }
    unsigned int hpk[4];
    #pragma unroll
    for (int i = 0; i < 4; i++)
        hpk[i] = (unsigned)f2bf(v[2*i]) | ((unsigned)f2bf(v[2*i+1]) << 16);
    *reinterpret_cast<uint4*>(h + (size_t)row * DD + lane * 8) =
        *reinterpret_cast<const uint4*>(hpk);

    #pragma unroll
    for (int off = 32; off > 0; off >>= 1) {
        sum += __shfl_xor(sum, off);
        sq  += __shfl_xor(sq, off);
    }
    float mu = sum * (1.f / DD);
    float var = sq * (1.f / DD) - mu * mu;
    float rstd = rsqrtf(var + 1e-5f);

    float s8[8], bi[8];
    *reinterpret_cast<float4*>(s8)     = *reinterpret_cast<const float4*>(ln_s + lane * 8);
    *reinterpret_cast<float4*>(s8 + 4) = *reinterpret_cast<const float4*>(ln_s + lane * 8 + 4);
    *reinterpret_cast<float4*>(bi)     = *reinterpret_cast<const float4*>(ln_b + lane * 8);
    *reinterpret_cast<float4*>(bi + 4) = *reinterpret_cast<const float4*>(ln_b + lane * 8 + 4);

    unsigned int pk[4];
    #pragma unroll
    for (int i = 0; i < 4; i++) {
        unsigned short lo = f2bf((v[2*i]   - mu) * rstd * s8[2*i]   + bi[2*i]);
        unsigned short hi = f2bf((v[2*i+1] - mu) * rstd * s8[2*i+1] + bi[2*i+1]);
        pk[i] = (unsigned)lo | ((unsigned)hi << 16);
    }
    *reinterpret_cast<uint4*>(g + (size_t)row * DD + lane * 8) =
        *reinterpret_cast<const uint4*>(pk);
}

// ---------------------------------------------------------------------------
// Kernel 2: LayerNorm (bf16 in, bf16 out). One wave per row, 4 rows/block.
// ---------------------------------------------------------------------------
__global__ __launch_bounds__(256)
void ln_kernel(const unsigned short* __restrict__ h,
               const float* __restrict__ scale,
               const float* __restrict__ bias,
               unsigned short* __restrict__ g)
{
    int w = threadIdx.x >> 6, lane = threadIdx.x & 63;
    int row = blockIdx.x * 4 + w;

    uint4 raw = *reinterpret_cast<const uint4*>(h + (size_t)row * DD + lane * 8);
    const unsigned* rw = reinterpret_cast<const unsigned*>(&raw);
    float v[8];
    #pragma unroll
    for (int i = 0; i < 4; i++) {
        v[2*i]   = __uint_as_float(rw[i] << 16);
        v[2*i+1] = __uint_as_float(rw[i] & 0xffff0000u);
    }

    float sum = 0.f, sq = 0.f;
    #pragma unroll
    for (int i = 0; i < 8; i++) { sum += v[i]; sq += v[i] * v[i]; }
    #pragma unroll
    for (int off = 32; off > 0; off >>= 1) {
        sum += __shfl_xor(sum, off);
        sq  += __shfl_xor(sq, off);
    }
    float mu = sum * (1.f / DD);
    float var = sq * (1.f / DD) - mu * mu;
    float rstd = rsqrtf(var + 1e-5f);

    float s[8], bi[8];
    *reinterpret_cast<float4*>(s)      = *reinterpret_cast<const float4*>(scale + lane * 8);
    *reinterpret_cast<float4*>(s + 4)  = *reinterpret_cast<const float4*>(scale + lane * 8 + 4);
    *reinterpret_cast<float4*>(bi)     = *reinterpret_cast<const float4*>(bias + lane * 8);
    *reinterpret_cast<float4*>(bi + 4) = *reinterpret_cast<const float4*>(bias + lane * 8 + 4);

    unsigned int pk[4];
    #pragma unroll
    for (int i = 0; i < 4; i++) {
        unsigned short lo = f2bf((v[2*i]   - mu) * rstd * s[2*i]   + bi[2*i]);
        unsigned short hi = f2bf((v[2*i+1] - mu) * rstd * s[2*i+1] + bi[2*i+1]);
        pk[i] = (unsigned)lo | ((unsigned)hi << 16);
    }
    *reinterpret_cast<uint4*>(g + (size_t)row * DD + lane * 8) =
        *reinterpret_cast<const uint4*>(pk);
}

// ---------------------------------------------------------------------------
// Kernel 3: MFMA GEMM (2-phase, MT=128) — champion path for qkv.
// ---------------------------------------------------------------------------
template<bool HAS_BIAS, bool GELU, bool RESID, bool QSCALE, int OMODE>
__global__ __launch_bounds__(256)
void gemm_mfma(const unsigned short* __restrict__ A,
               const unsigned short* __restrict__ W,
               const float* __restrict__ bias,
               const unsigned short* __restrict__ resid,
               void* __restrict__ Cv,
               int Nn, int Kk)
{
    __shared__ unsigned short As[2][128 * 64];
    __shared__ unsigned short Bs[2][128 * 64];

    int t = threadIdx.x;
    int w = t >> 6, lane = t & 63;
    int wr = w >> 1, wc = w & 1;
    int l15 = lane & 15, l4 = lane >> 4;
    int m0 = blockIdx.y * 128, n0 = blockIdx.x * 128;

    int lrow = lane >> 3;
    int segp = (lane & 7) ^ lrow;

    float4v acc[4][4];
    #pragma unroll
    for (int i = 0; i < 4; i++)
        #pragma unroll
        for (int j = 0; j < 4; j++)
            acc[i][j] = (float4v){0.f, 0.f, 0.f, 0.f};

    #define STAGE(buf, k0) do {                                                   \
        _Pragma("unroll")                                                         \
        for (int i_ = 0; i_ < 4; i_++) {                                          \
            int r_ = i_ * 32 + w * 8 + lrow;                                      \
            __builtin_amdgcn_global_load_lds(                                     \
                (glb_u32*)(A + (size_t)(m0 + r_) * Kk + (k0) + segp * 8),         \
                (lds_u32*)(As[buf] + i_ * 2048 + w * 512), 16, 0, 0);             \
            __builtin_amdgcn_global_load_lds(                                     \
                (glb_u32*)(W + (size_t)(n0 + r_) * Kk + (k0) + segp * 8),         \
                (lds_u32*)(Bs[buf] + i_ * 2048 + w * 512), 16, 0, 0);             \
        } } while (0)

    int nk = Kk >> 6;
    STAGE(0, 0);
    for (int kt = 0; kt < nk; kt++) {
        int cur = kt & 1;
        if (kt + 1 < nk) {
            STAGE(cur ^ 1, (kt + 1) << 6);
            __builtin_amdgcn_sched_barrier(0);
            asm volatile("s_waitcnt vmcnt(8)");
            __builtin_amdgcn_sched_barrier(0);
        } else {
            __builtin_amdgcn_sched_barrier(0);
            asm volatile("s_waitcnt vmcnt(0)");
            __builtin_amdgcn_sched_barrier(0);
        }
        __builtin_amdgcn_s_barrier();

        const char* asb = (const char*)As[cur];
        const char* bsb = (const char*)Bs[cur];
        #pragma unroll
        for (int kc = 0; kc < 2; kc++) {
            short8v af[4], bfr[4];
            #pragma unroll
            for (int mf = 0; mf < 4; mf++) {
                int row = wr * 64 + mf * 16 + l15;
                int off = (row * 128 + kc * 64 + l4 * 16) ^ ((row & 7) << 4);
                af[mf] = *reinterpret_cast<const short8v*>(asb + off);
            }
            #pragma unroll
            for (int nf = 0; nf < 4; nf++) {
                int row = wc * 64 + nf * 16 + l15;
                int off = (row * 128 + kc * 64 + l4 * 16) ^ ((row & 7) << 4);
                bfr[nf] = *reinterpret_cast<const short8v*>(bsb + off);
            }
            #pragma unroll
            for (int mf = 0; mf < 4; mf++)
                #pragma unroll
                for (int nf = 0; nf < 4; nf++)
                    acc[mf][nf] = __builtin_amdgcn_mfma_f32_16x16x32_bf16(
                        af[mf], bfr[nf], acc[mf][nf], 0, 0, 0);
        }
        __builtin_amdgcn_s_barrier();
    }
    #undef STAGE

    #pragma unroll
    for (int mf = 0; mf < 4; mf++)
        #pragma unroll
        for (int nf = 0; nf < 4; nf++)
            #pragma unroll
            for (int r = 0; r < 4; r++) {
                int m = m0 + wr * 64 + mf * 16 + l4 * 4 + r;
                int n = n0 + wc * 64 + nf * 16 + l15;
                if (n < Nn) {
                    float v = acc[mf][nf][r];
                    if (HAS_BIAS) v += bias[n];
                    if (GELU)     v = gelu_tanh(v);
                    if (RESID)    v += bf2f(resid[(size_t)m * Nn + n]);
                    if (QSCALE && n < DD) v *= C8;
                    if (OMODE == 1)
                        ((unsigned short*)Cv)[(size_t)m * Nn + n] = f2bf(v);
                    else
                        ((float*)Cv)[(size_t)m * Nn + n] = v;
                }
            }
}

// ---------------------------------------------------------------------------
// Kernel 3c: MT=64 GEMM with 3-buffer ring + stage-ahead-2 (ao/ffn2/logits).
// ---------------------------------------------------------------------------
template<bool HAS_BIAS, bool GELU, bool RESID, int OMODE>
__global__ __launch_bounds__(128)
void gemm_mfma64_d3(const unsigned short* __restrict__ A,
                    const unsigned short* __restrict__ W,
                    const float* __restrict__ bias,
                    const unsigned short* __restrict__ resid,
                    void* __restrict__ Cv,
                    int Nn, int Kk)
{
    __shared__ unsigned short As[3][64 * 64];    // 8 KB each
    __shared__ unsigned short Bs[3][128 * 64];   // 16 KB each

    int t = threadIdx.x;
    int w = t >> 6, lane = t & 63;               // w in [0,2)
    int wc = w;                                  // wave n-half; wr = 0
    int l15 = lane & 15, l4 = lane >> 4;
    int m0 = blockIdx.y * 64, n0 = blockIdx.x * 128;

    int lrow = lane >> 3;
    int segp = (lane & 7) ^ lrow;

    float4v acc[4][4];
    #pragma unroll
    for (int i = 0; i < 4; i++)
        #pragma unroll
        for (int j = 0; j < 4; j++)
            acc[i][j] = (float4v){0.f, 0.f, 0.f, 0.f};

    #define STAGE64(buf, k0) do {                                                 \
        _Pragma("unroll")                                                         \
        for (int i_ = 0; i_ < 4; i_++) {                                          \
            int r_ = i_ * 16 + w * 8 + lrow;                                      \
            __builtin_amdgcn_global_load_lds(                                     \
                (glb_u32*)(A + (size_t)(m0 + r_) * Kk + (k0) + segp * 8),         \
                (lds_u32*)(As[buf] + i_ * 1024 + w * 512), 16, 0, 0);             \
        }                                                                         \
        _Pragma("unroll")                                                         \
        for (int i_ = 0; i_ < 8; i_++) {                                          \
            int r_ = i_ * 16 + w * 8 + lrow;                                      \
            __builtin_amdgcn_global_load_lds(                                     \
                (glb_u32*)(W + (size_t)(n0 + r_) * Kk + (k0) + segp * 8),         \
                (lds_u32*)(Bs[buf] + i_ * 1024 + w * 512), 16, 0, 0);             \
        } } while (0)

    int nk = Kk >> 6;                            // >= 8 for all uses
    STAGE64(0, 0);
    STAGE64(1, 64);

    int cur = 0;
    for (int kt = 0; kt < nk; kt++) {
        if (kt + 2 < nk) {
            int sb = cur + 2; if (sb >= 3) sb -= 3;
            STAGE64(sb, (kt + 2) << 6);
        }
        __builtin_amdgcn_sched_barrier(0);
        int rem = nk - 1 - kt;
        if (rem >= 2)      asm volatile("s_waitcnt vmcnt(24)");
        else if (rem == 1) asm volatile("s_waitcnt vmcnt(12)");
        else               asm volatile("s_waitcnt vmcnt(0)");
        __builtin_amdgcn_sched_barrier(0);
        __builtin_amdgcn_s_barrier();            // publish tile kt

        const char* asb = (const char*)As[cur];
        const char* bsb = (const char*)Bs[cur];
        #pragma unroll
        for (int kc = 0; kc < 2; kc++) {
            short8v af[4], bfr[4];
            #pragma unroll
            for (int mf = 0; mf < 4; mf++) {
                int row = mf * 16 + l15;
                int off = (row * 128 + kc * 64 + l4 * 16) ^ ((row & 7) << 4);
                af[mf] = *reinterpret_cast<const short8v*>(asb + off);
            }
            #pragma unroll
            for (int nf = 0; nf < 4; nf++) {
                int row = wc * 64 + nf * 16 + l15;
                int off = (row * 128 + kc * 64 + l4 * 16) ^ ((row & 7) << 4);
                bfr[nf] = *reinterpret_cast<const short8v*>(bsb + off);
            }
            __builtin_amdgcn_s_setprio(1);
            #pragma unroll
            for (int mf = 0; mf < 4; mf++)
                #pragma unroll
                for (int nf = 0; nf < 4; nf++)
                    acc[mf][nf] = __builtin_amdgcn_mfma_f32_16x16x32_bf16(
                        af[mf], bfr[nf], acc[mf][nf], 0, 0, 0);
            __builtin_amdgcn_s_setprio(0);
        }
        __builtin_amdgcn_s_barrier();            // fence readers before overwrite
        cur = cur + 1; if (cur >= 3) cur -= 3;
    }
    #undef STAGE64

    #pragma unroll
    for (int mf = 0; mf < 4; mf++)
        #pragma unroll
        for (int nf = 0; nf < 4; nf++)
            #pragma unroll
            for (int r = 0; r < 4; r++) {
                int m = m0 + mf * 16 + l4 * 4 + r;
                int n = n0 + wc * 64 + nf * 16 + l15;
                if (n < Nn) {
                    float v = acc[mf][nf][r];
                    if (HAS_BIAS) v += bias[n];
                    if (GELU)     v = gelu_tanh(v);
                    if (RESID)    v += bf2f(resid[(size_t)m * Nn + n]);
                    if (OMODE == 1)
                        ((unsigned short*)Cv)[(size_t)m * Nn + n] = f2bf(v);
                    else
                        ((float*)Cv)[(size_t)m * Nn + n] = v;
                }
            }
}

// ---------------------------------------------------------------------------
// Kernel 3b: deep-pipelined 256x256 MFMA GEMM (ffn1) — unchanged from R17.
// ---------------------------------------------------------------------------
__global__ __launch_bounds__(512, 1)
void gemm_mfma_256(const unsigned short* __restrict__ A,
                   const unsigned short* __restrict__ W,
                   const float* __restrict__ bias,
                   unsigned short* __restrict__ C,
                   int Nn, int Kk)
{
    __shared__ unsigned short As2[2][256 * 64];   // 64 KB
    __shared__ unsigned short Bs2[2][256 * 64];   // 64 KB

    int t = threadIdx.x;
    int w = t >> 6, lane = t & 63;                // w in [0,8)
    int wr = w >> 2, wc = w & 3;                  // 2M x 4N wave grid
    int l15 = lane & 15, l4 = lane >> 4;

    int flat = blockIdx.x;
    int bx = flat >> 5, by = flat & 31;           // flat%8 == by%8 (XCD co-locate)
    int m0 = by * 256, n0 = bx * 256;

    int lrow8 = lane >> 3;
    int grow = w * 8 + lrow8;
    int segp = (lane & 7) ^ lrow8;

    float4v acc[8][4];
    #pragma unroll
    for (int i = 0; i < 8; i++)
        #pragma unroll
        for (int j = 0; j < 4; j++)
            acc[i][j] = (float4v){0.f, 0.f, 0.f, 0.f};

    #define STG_HALF(P, RB, K0, L) do {                                           \
        __builtin_amdgcn_global_load_lds(                                         \
            (glb_u32*)(P + (size_t)((RB) + grow) * Kk + (K0) + segp * 8),         \
            (lds_u32*)((L) + w * 512), 16, 0, 0);                                 \
        __builtin_amdgcn_global_load_lds(                                         \
            (glb_u32*)(P + (size_t)((RB) + 64 + grow) * Kk + (K0) + segp * 8),    \
            (lds_u32*)((L) + 4096 + w * 512), 16, 0, 0);                          \
    } while (0)

    #define STG_TILE(buf, K0) do {                                               \
        STG_HALF(A, m0,       (K0), As2[buf]);                                   \
        STG_HALF(A, m0 + 128, (K0), As2[buf] + 8192);                            \
        STG_HALF(W, n0,       (K0), Bs2[buf]);                                   \
        STG_HALF(W, n0 + 128, (K0), Bs2[buf] + 8192);                            \
    } while (0)

    int nk = Kk >> 6;
    STG_TILE(0, 0);

    for (int kt = 0; kt < nk; kt++) {
        int cur = kt & 1;
        if (kt + 1 < nk) {
            STG_TILE(cur ^ 1, (kt + 1) << 6);
            __builtin_amdgcn_sched_barrier(0);
            asm volatile("s_waitcnt vmcnt(8)");
            __builtin_amdgcn_sched_barrier(0);
        } else {
            __builtin_amdgcn_sched_barrier(0);
            asm volatile("s_waitcnt vmcnt(0)");
            __builtin_amdgcn_sched_barrier(0);
        }
        __builtin_amdgcn_s_barrier();

        const char* asb = (const char*)As2[cur];
        const char* bsb = (const char*)Bs2[cur];
        short8v af[4], bfr[4];

        #pragma unroll
        for (int ph = 0; ph < 4; ph++) {
            int kc = ph >> 1;
            int mh = ph & 1;
            if (mh == 0) {
                #pragma unroll
                for (int nf = 0; nf < 4; nf++) {
                    int row = wc * 64 + nf * 16 + l15;
                    int off = (row * 128 + kc * 64 + l4 * 16) ^ ((row & 7) << 4);
                    bfr[nf] = *reinterpret_cast<const short8v*>(bsb + off);
                }
            }
            #pragma unroll
            for (int mf = 0; mf < 4; mf++) {
                int row = wr * 128 + (mh * 4 + mf) * 16 + l15;
                int off = (row * 128 + kc * 64 + l4 * 16) ^ ((row & 7) << 4);
                af[mf] = *reinterpret_cast<const short8v*>(asb + off);
            }
            __builtin_amdgcn_s_setprio(1);
            #pragma unroll
            for (int mf = 0; mf < 4; mf++)
                #pragma unroll
                for (int nf = 0; nf < 4; nf++)
                    acc[mh * 4 + mf][nf] = __builtin_amdgcn_mfma_f32_16x16x32_bf16(
                        af[mf], bfr[nf], acc[mh * 4 + mf][nf], 0, 0, 0);
            __builtin_amdgcn_s_setprio(0);
        }
        __builtin_amdgcn_s_barrier();
    }
    #undef STG_TILE
    #undef STG_HALF

    #pragma unroll
    for (int mf = 0; mf < 8; mf++)
        #pragma unroll
        for (int nf = 0; nf < 4; nf++)
            #pragma unroll
            for (int r = 0; r < 4; r++) {
                int m = m0 + wr * 128 + mf * 16 + l4 * 4 + r;
                int n = n0 + wc * 64 + nf * 16 + l15;
                float v = acc[mf][nf][r] + bias[n];
                v = gelu_tanh(v);
                C[(size_t)m * Nn + n] = f2bf(v);
            }
}

// ---------------------------------------------------------------------------
// Kernel 4: MFMA flash attention (R12/R18 champion configuration)
// ---------------------------------------------------------------------------
__global__ __launch_bounds__(512, 2)
void attn_mfma(const unsigned short* __restrict__ qkv, unsigned short* __restrict__ o)
{
    __shared__ unsigned short Kl[2][128 * 64];
    __shared__ unsigned short Vs[2][128 * 64];
    __shared__ float Scl[8][16];

    int t = threadIdx.x, w = t >> 6, lane = t & 63;
    int l15 = lane & 15, l4 = lane >> 4;

    int flat = blockIdx.x;
    int swz = (flat & 7) * 64 + (flat >> 3);
    int qt = swz & 15, hh = (swz >> 4) & 7, b = swz >> 7;

    int q0 = qt * 128 + w * 16;
    const int RS = 3 * DD; // 1536

    short8v qf[2];
    #pragma unroll
    for (int dh = 0; dh < 2; dh++) {
        size_t addr = (size_t)(b * LL + q0 + l15) * RS + hh * HDIM + dh * 32 + l4 * 8;
        qf[dh] = *reinterpret_cast<const short8v*>(qkv + addr);
    }

    float4v o_acc[4];
    #pragma unroll
    for (int dt = 0; dt < 4; dt++) o_acc[dt] = (float4v){0.f, 0.f, 0.f, 0.f};
    float l_run = 0.f;

    int lrow8 = lane >> 3;
    int ksegp = (lane & 7) ^ lrow8;
    int rho = w * 8 + lrow8;
    int kappa = ((rho >> 5) << 5) | (((rho >> 4) & 1) << 2)
              | (((rho >> 2) & 3) << 3) | (rho & 3);
    int vrow = ((t >> 5) << 2) | ((t >> 1) & 3);
    int vseg = (((t >> 3) & 3) << 1) | (t & 1);
    const unsigned short* kgl = qkv + (size_t)(b * LL + kappa) * RS
                              + hh * HDIM + DD + ksegp * 8;
    const unsigned short* vgl = qkv + (size_t)(b * LL + vrow) * RS
                              + hh * HDIM + 2 * DD + vseg * 8;
    const int halfstep = 64 * RS;
    const int step = 128 * RS;

    #define ASTAGE(buf) do {                                                      \
        __builtin_amdgcn_global_load_lds((glb_u32*)kgl,                           \
            (lds_u32*)(Kl[buf] + w * 512), 16, 0, 0);                             \
        __builtin_amdgcn_global_load_lds((glb_u32*)(kgl + halfstep),              \
            (lds_u32*)(Kl[buf] + 4096 + w * 512), 16, 0, 0);                      \
        __builtin_amdgcn_global_load_lds((glb_u32*)vgl,                           \
            (lds_u32*)(Vs[buf] + w * 512), 16, 0, 0);                             \
        __builtin_amdgcn_global_load_lds((glb_u32*)(vgl + halfstep),              \
            (lds_u32*)(Vs[buf] + 4096 + w * 512), 16, 0, 0);                      \
        kgl += step; vgl += step; } while (0)

    unsigned vtrbase = lds_addr(Vs) + ((lane >> 4) << 10)
                     + (((lane >> 2) & 3) << 5) + ((lane & 3) << 3);

    ASTAGE(0);
    asm volatile("s_waitcnt vmcnt(0)");
    __syncthreads();

    for (int kb = 0; kb < LL / 128; kb++) {
        int cur = kb & 1;
        if (kb + 1 < LL / 128) ASTAGE(cur ^ 1);

        #pragma unroll
        for (int hf = 0; hf < 2; hf++) {
            const char* klc = (const char*)Kl[cur] + hf * 8192;
            unsigned vb = vtrbase + cur * 16384 + hf * 8192;

            float4v s_acc[4];
            __builtin_amdgcn_s_setprio(1);
            #pragma unroll
            for (int nt = 0; nt < 4; nt++) {
                s_acc[nt] = (float4v){0.f, 0.f, 0.f, 0.f};
                #pragma unroll
                for (int dh = 0; dh < 2; dh++) {
                    int row = nt * 16 + l15;
                    int off = (row * 128 + dh * 64 + l4 * 16) ^ ((row & 7) << 4);
                    short8v kf = *reinterpret_cast<const short8v*>(klc + off);
                    s_acc[nt] = __builtin_amdgcn_mfma_f32_16x16x32_bf16(kf, qf[dh], s_acc[nt], 0, 0, 0);
                }
            }
            __builtin_amdgcn_s_setprio(0);

            unsigned long long a0, a1, a2, a3, a4, a5, a6, a7;
            unsigned long long b0, b1, b2, b3, b4, b5, b6, b7;
            unsigned ab0 = vb, ab1 = vb + 4096;
            asm volatile("ds_read_b64_tr_b16 %0, %1" : "=v"(a0) : "v"(ab0));
            asm volatile("ds_read_b64_tr_b16 %0, %1" : "=v"(a1) : "v"(ab0 + 512));
            asm volatile("ds_read_b64_tr_b16 %0, %1" : "=v"(a2) : "v"(ab0 + 128));
            asm volatile("ds_read_b64_tr_b16 %0, %1" : "=v"(a3) : "v"(ab0 + 640));
            asm volatile("ds_read_b64_tr_b16 %0, %1" : "=v"(a4) : "v"(ab0 + 256));
            asm volatile("ds_read_b64_tr_b16 %0, %1" : "=v"(a5) : "v"(ab0 + 768));
            asm volatile("ds_read_b64_tr_b16 %0, %1" : "=v"(a6) : "v"(ab0 + 384));
            asm volatile("ds_read_b64_tr_b16 %0, %1" : "=v"(a7) : "v"(ab0 + 896));
            asm volatile("ds_read_b64_tr_b16 %0, %1" : "=v"(b0) : "v"(ab1));
            asm volatile("ds_read_b64_tr_b16 %0, %1" : "=v"(b1) : "v"(ab1 + 512));
            asm volatile("ds_read_b64_tr_b16 %0, %1" : "=v"(b2) : "v"(ab1 + 128));
            asm volatile("ds_read_b64_tr_b16 %0, %1" : "=v"(b3) : "v"(ab1 + 640));
            asm volatile("ds_read_b64_tr_b16 %0, %1" : "=v"(b4) : "v"(ab1 + 256));
            asm volatile("ds_read_b64_tr_b16 %0, %1" : "=v"(b5) : "v"(ab1 + 768));
            asm volatile("ds_read_b64_tr_b16 %0, %1" : "=v"(b6) : "v"(ab1 + 384));
            asm volatile("ds_read_b64_tr_b16 %0, %1" : "=v"(b7) : "v"(ab1 + 896));

            union { unsigned u[4]; short8v v; } pf0u, pf1u;
            float ps;
            {
                float p0 = __builtin_amdgcn_exp2f(s_acc[0][0]);
                float p1 = __builtin_amdgcn_exp2f(s_acc[0][1]);
                float p2 = __builtin_amdgcn_exp2f(s_acc[0][2]);
                float p3 = __builtin_amdgcn_exp2f(s_acc[0][3]);
                float p4 = __builtin_amdgcn_exp2f(s_acc[1][0]);
                float p5 = __builtin_amdgcn_exp2f(s_acc[1][1]);
                float p6 = __builtin_amdgcn_exp2f(s_acc[1][2]);
                float p7 = __builtin_amdgcn_exp2f(s_acc[1][3]);
                asm("v_cvt_pk_bf16_f32 %0, %1, %2" : "=v"(pf0u.u[0]) : "v"(p0), "v"(p1));
                asm("v_cvt_pk_bf16_f32 %0, %1, %2" : "=v"(pf0u.u[1]) : "v"(p2), "v"(p3));
                asm("v_cvt_pk_bf16_f32 %0, %1, %2" : "=v"(pf0u.u[2]) : "v"(p4), "v"(p5));
                asm("v_cvt_pk_bf16_f32 %0, %1, %2" : "=v"(pf0u.u[3]) : "v"(p6), "v"(p7));
                ps = ((p0 + p1) + (p2 + p3)) + ((p4 + p5) + (p6 + p7));
            }
            {
                float p0 = __builtin_amdgcn_exp2f(s_acc[2][0]);
                float p1 = __builtin_amdgcn_exp2f(s_acc[2][1]);
                float p2 = __builtin_amdgcn_exp2f(s_acc[2][2]);
                float p3 = __builtin_amdgcn_exp2f(s_acc[2][3]);
                float p4 = __builtin_amdgcn_exp2f(s_acc[3][0]);
                float p5 = __builtin_amdgcn_exp2f(s_acc[3][1]);
                float p6 = __builtin_amdgcn_exp2f(s_acc[3][2]);
                float p7 = __builtin_amdgcn_exp2f(s_acc[3][3]);
                asm("v_cvt_pk_bf16_f32 %0, %1, %2" : "=v"(pf1u.u[0]) : "v"(p0), "v"(p1));
                asm("v_cvt_pk_bf16_f32 %0, %1, %2" : "=v"(pf1u.u[1]) : "v"(p2), "v"(p3));
                asm("v_cvt_pk_bf16_f32 %0, %1, %2" : "=v"(pf1u.u[2]) : "v"(p4), "v"(p5));
                asm("v_cvt_pk_bf16_f32 %0, %1, %2" : "=v"(pf1u.u[3]) : "v"(p6), "v"(p7));
                ps += ((p0 + p1) + (p2 + p3)) + ((p4 + p5) + (p6 + p7));
            }
            l_run += ps;

            union { unsigned long long q[2]; short8v v; } u0, u1, u2, u3;
            asm volatile("s_waitcnt lgkmcnt(8)");
            __builtin_amdgcn_sched_barrier(0);
            __builtin_amdgcn_s_setprio(1);
            u0.q[0] = a0; u0.q[1] = a1;
            u1.q[0] = a2; u1.q[1] = a3;
            o_acc[0] = __builtin_amdgcn_mfma_f32_16x16x32_bf16(pf0u.v, u0.v, o_acc[0], 0, 0, 0);
            o_acc[1] = __builtin_amdgcn_mfma_f32_16x16x32_bf16(pf0u.v, u1.v, o_acc[1], 0, 0, 0);
            asm volatile("s_waitcnt lgkmcnt(4)");
            __builtin_amdgcn_sched_barrier(0);
            u2.q[0] = a4; u2.q[1] = a5;
            u3.q[0] = a6; u3.q[1] = a7;
            o_acc[2] = __builtin_amdgcn_mfma_f32_16x16x32_bf16(pf0u.v, u2.v, o_acc[2], 0, 0, 0);
            o_acc[3] = __builtin_amdgcn_mfma_f32_16x16x32_bf16(pf0u.v, u3.v, o_acc[3], 0, 0, 0);
            asm volatile("s_waitcnt lgkmcnt(0)");
            __builtin_amdgcn_sched_barrier(0);
            u0.q[0] = b0; u0.q[1] = b1;
            u1.q[0] = b2; u1.q[1] = b3;
            u2.q[0] = b4; u2.q[1] = b5;
            u3.q[0] = b6; u3.q[1] = b7;
            o_acc[0] = __builtin_amdgcn_mfma_f32_16x16x32_bf16(pf1u.v, u0.v, o_acc[0], 0, 0, 0);
            o_acc[1] = __builtin_amdgcn_mfma_f32_16x16x32_bf16(pf1u.v, u1.v, o_acc[1], 0, 0, 0);
            o_acc[2] = __builtin_amdgcn_mfma_f32_16x16x32_bf16(pf1u.v, u2.v, o_acc[2], 0, 0, 0);
            o_acc[3] = __builtin_amdgcn_mfma_f32_16x16x32_bf16(pf1u.v, u3.v, o_acc[3], 0, 0, 0);
            __builtin_amdgcn_s_setprio(0);
        }

        asm volatile("s_waitcnt vmcnt(0)");
        __syncthreads();
    }
    #undef ASTAGE

    float lt = l_run;
    lt += __shfl_xor(lt, 16);
    lt += __shfl_xor(lt, 32);
    if (l4 == 0) Scl[w][l15] = 1.f / lt;
    float4 iv = *reinterpret_cast<const float4*>(&Scl[w][l4 * 4]);
    float invs[4] = {iv.x, iv.y, iv.z, iv.w};
    #pragma unroll
    for (int r = 0; r < 4; r++) {
        int qg = q0 + l4 * 4 + r;
        #pragma unroll
        for (int dt = 0; dt < 4; dt++) {
            o[(size_t)(b * LL + qg) * DD + hh * HDIM + dt * 16 + l15] =
                f2bf(o_acc[dt][r] * invs[r]);
        }
    }
}

// ---------------------------------------------------------------------------
// Driver
// ---------------------------------------------------------------------------
extern "C" void kernel_launch(void* const* d_in, const int* in_sizes, int n_in,
                              void* d_out, int out_size, void* d_ws, size_t ws_size,
                              hipStream_t stream)
{
    const float* emb    = (const float*)d_in[0];
    const float* ent_w  = (const float*)d_in[1];
    const float* ent_b  = (const float*)d_in[2];
    const float* qkv_w  = (const float*)d_in[3];
    const float* qkv_b  = (const float*)d_in[4];
    const float* ao_w   = (const float*)d_in[5];
    const float* ao_b   = (const float*)d_in[6];
    const float* ln1_s  = (const float*)d_in[7];
    const float* ln1_b  = (const float*)d_in[8];
    const float* ln2_s  = (const float*)d_in[9];
    const float* ln2_b  = (const float*)d_in[10];
    const float* ff1_w  = (const float*)d_in[11];
    const float* ff1_b  = (const float*)d_in[12];
    const float* ff2_w  = (const float*)d_in[13];
    const float* ff2_b  = (const float*)d_in[14];
    const float* out_w  = (const float*)d_in[15];
    const int*   x      = (const int*)d_in[16];
    // d_in[17] = patch_lengths : dead code in the reference

    float* out = (float*)d_out;

    const int NQW = NLAYER * 3 * DD * DD;
    const int NAW = NLAYER * DD * DD;
    const int NF1 = NLAYER * 4 * DD * DD;
    const int NF2 = NLAYER * DD * 4 * DD;

    char* p = (char*)d_ws;
    unsigned short* wq  = (unsigned short*)p; p += (size_t)NQW * 2;
    unsigned short* wa  = (unsigned short*)p; p += (size_t)NAW * 2;
    unsigned short* w1  = (unsigned short*)p; p += (size_t)NF1 * 2;
    unsigned short* w2  = (unsigned short*)p; p += (size_t)NF2 * 2;
    unsigned short* wob = (unsigned short*)p; p += (size_t)VPAD * DD * 2;
    unsigned short* h   = (unsigned short*)p; p += (size_t)MM * DD * 2;   // bf16 residual
    unsigned short* gb  = (unsigned short*)p; p += (size_t)MM * DD * 2;
    unsigned short* ob  = (unsigned short*)p; p += (size_t)MM * DD * 2;
    unsigned short* bb  = (unsigned short*)p; p += (size_t)MM * 4 * DD * 2; // qkv / ffn

    dim3 blk(256);

    cvt_all_kernel<<<E4 / 1024, blk, 0, stream>>>(qkv_w, ao_w, ff1_w, ff2_w, out_w, wq);

    embed_ln_kernel<<<MM / 4, blk, 0, stream>>>(x, emb, ent_w, ent_b,
                                                ln1_s, ln1_b, h, gb);

    for (int layer = 0; layer < NLAYER; layer++) {
        const unsigned short* qw = wq + (size_t)layer * 3 * DD * DD;
        const unsigned short* aw = wa + (size_t)layer * DD * DD;
        const unsigned short* f1 = w1 + (size_t)layer * 4 * DD * DD;
        const unsigned short* f2 = w2 + (size_t)layer * DD * 4 * DD;
        const float* qb  = qkv_b + (size_t)layer * 3 * DD;
        const float* ab  = ao_b  + (size_t)layer * DD;
        const float* l1s = ln1_s + (size_t)layer * DD;
        const float* l1b = ln1_b + (size_t)layer * DD;
        const float* l2s = ln2_s + (size_t)layer * DD;
        const float* l2b = ln2_b + (size_t)layer * DD;
        const float* f1b = ff1_b + (size_t)layer * 4 * DD;
        const float* f2b = ff2_b + (size_t)layer * DD;

        // LN1 (layer 0 fused into embed_ln_kernel)
        if (layer > 0)
            ln_kernel<<<MM / 4, blk, 0, stream>>>(h, l1s, l1b, gb);

        // qkv = gb @ qw^T + qb -> bb (bf16) [MM,1536], Q cols pre-scaled by C8
        {
            dim3 grid((3 * DD) / 128, MM / 128);
            gemm_mfma<true, false, false, true, 1><<<grid, 256, 0, stream>>>(
                gb, qw, qb, nullptr, bb, 3 * DD, DD);
        }

        // attention: bb -> ob (bf16)
        attn_mfma<<<512, 512, 0, stream>>>(bb, ob);

        // h = h + ob @ aw^T + ab  (bf16 out; MT=64 3-buffer deep pipe)
        {
            dim3 grid(DD / 128, MM / 64);
            gemm_mfma64_d3<true, false, true, 1><<<grid, 128, 0, stream>>>(
                ob, aw, ab, h, h, DD, DD);
        }

        // LN2: h -> gb
        ln_kernel<<<MM / 4, blk, 0, stream>>>(h, l2s, l2b, gb);

        // ffn1: bb = gelu(gb @ f1^T + f1b) (bf16) [MM,2048] -- deep-pipelined 256^2
        gemm_mfma_256<<<(MM / 256) * ((4 * DD) / 256), 512, 0, stream>>>(
            gb, f1, f1b, bb, 4 * DD, DD);

        // ffn2: h = h + bb @ f2^T + f2b  (bf16 out; MT=64 3-buffer deep pipe)
        {
            dim3 grid(DD / 128, MM / 64);
            gemm_mfma64_d3<true, false, true, 1><<<grid, 128, 0, stream>>>(
                bb, f2, f2b, h, h, DD, 4 * DD);
        }
    }

    // logits = h @ wob^T [MM, 258] via MFMA on padded weight (MT=64 3-buffer)
    {
        dim3 grid(VPAD / 128, MM / 64);
        gemm_mfma64_d3<false, false, false, 0><<<grid, 128, 0, stream>>>(
            h, wob, nullptr, nullptr, out, VV, DD);
    }
}